// Round 1
// baseline (321.163 us; speedup 1.0000x reference)
//
#include <hip/hip_runtime.h>
#include <hip/hip_bf16.h>
#include <cstddef>

#define B_   256
#define P_   196
#define DE_  2048
#define DD_  512
#define DA_  512
#define M_   (B_*P_)   // 50176

#define BM   64
#define KT   32        // K per MFMA step

typedef __attribute__((ext_vector_type(4))) float f32x4;
typedef __attribute__((ext_vector_type(8))) short s16x8;

// ---------------------------------------------------------------------------
// Kernel 0: pack W_enc [K=2048][N=512] fp32 -> bf16 fragment-ready layout
// out[kt][n][kk] : kt = k/32 (64 tiles), n = 0..511, kk = k%32
// ---------------------------------------------------------------------------
__global__ void pack_wenc(const float* __restrict__ W, __hip_bfloat16* __restrict__ out) {
    __shared__ float lds[KT][128 + 1];   // +1 pad: avoid 32-way conflict on transposed read
    const int kt = blockIdx.x;           // 0..63
    const int n0 = blockIdx.y * 128;     // 0..3 * 128
    const int t  = threadIdx.x;          // 0..255
#pragma unroll
    for (int i = 0; i < 16; ++i) {
        int e  = t + i * 256;            // 0..4095
        int kl = e >> 7;                 // 0..31
        int nl = e & 127;
        lds[kl][nl] = W[(size_t)(kt * KT + kl) * DA_ + n0 + nl];
    }
    __syncthreads();
#pragma unroll
    for (int i = 0; i < 16; ++i) {
        int e  = t + i * 256;
        int nl = e >> 5;                 // 0..127
        int kk = e & 31;
        out[((size_t)kt * DA_ + n0 + nl) * KT + kk] = __float2bfloat16(lds[kk][nl]);
    }
}

// ---------------------------------------------------------------------------
// Kernel 1: att2p[b][a] = decoder_hidden[b,:] @ W_dec[:,a] + b_dec[a] + b_enc[a]
// ---------------------------------------------------------------------------
__global__ __launch_bounds__(512) void att2_kernel(
        const float* __restrict__ dh, const float* __restrict__ W_dec,
        const float* __restrict__ b_dec, const float* __restrict__ b_enc,
        float* __restrict__ att2p) {
    __shared__ float s_dh[DD_];
    const int b = blockIdx.x;
    const int a = threadIdx.x;           // 0..511
    s_dh[a] = dh[(size_t)b * DD_ + a];
    __syncthreads();
    float acc = 0.f;
#pragma unroll 8
    for (int k = 0; k < DD_; ++k)
        acc += s_dh[k] * W_dec[(size_t)k * DA_ + a];
    att2p[(size_t)b * DA_ + a] = acc + b_dec[a] + b_enc[a];
}

// ---------------------------------------------------------------------------
// Kernel 2: big GEMM (M=50176, K=2048, N=512) bf16 MFMA, fused epilogue:
//   att[R] = sum_n relu(att1[R][n] + att2p[b][n]) * Wfull[n] + bfull
// Block: 512 threads (8 waves), tile 64 x 512 (full N), wave w owns n in [w*64, w*64+64)
// ---------------------------------------------------------------------------
__global__ __launch_bounds__(512, 1) void gemm_att(
        const float* __restrict__ enc, const __hip_bfloat16* __restrict__ Bp,
        const float* __restrict__ att2p, const float* __restrict__ Wfull,
        const float* __restrict__ bfull, float* __restrict__ att) {
    __shared__ __hip_bfloat16 a_lds[BM * KT];    // [row][kk]  4 KB
    __shared__ __hip_bfloat16 b_lds[DA_ * KT];   // [n][kk]   32 KB
    __shared__ float red[BM][8];                 // per-wave row partials, 2 KB

    const int tid  = threadIdx.x;
    const int wave = tid >> 6;
    const int lane = tid & 63;
    const int g    = lane >> 4;       // 0..3  (k-group)
    const int c    = lane & 15;       // 0..15 (row for A-frag / col for B-frag)
    const int block_row = blockIdx.x * BM;
    const int nbase = wave * 64;

    f32x4 acc[4][4] = {};             // [mt][nt], zero-init

    for (int kt = 0; kt < DE_ / KT; ++kt) {
        __syncthreads();              // protect LDS from previous iteration's readers
        // --- stage A: 64 rows x 32 k, fp32 -> bf16 ---
        {
            const int r  = tid >> 3;          // 0..63
            const int kk = (tid & 7) * 4;     // 0,4,..28
            const float* src = enc + (size_t)(block_row + r) * DE_ + kt * KT + kk;
            f32x4 v = *reinterpret_cast<const f32x4*>(src);
            __hip_bfloat16* d = a_lds + r * KT + kk;
            d[0] = __float2bfloat16(v.x);
            d[1] = __float2bfloat16(v.y);
            d[2] = __float2bfloat16(v.z);
            d[3] = __float2bfloat16(v.w);
        }
        // --- stage B: contiguous 32 KB copy (packed layout == LDS layout) ---
        {
            const s16x8* src = reinterpret_cast<const s16x8*>(Bp + (size_t)kt * DA_ * KT);
            s16x8* dst = reinterpret_cast<s16x8*>(b_lds);
#pragma unroll
            for (int i = 0; i < 4; ++i)
                dst[tid + i * 512] = src[tid + i * 512];
        }
        __syncthreads();
        // --- fragments + MFMA ---
        s16x8 afrag[4], bfrag[4];
#pragma unroll
        for (int mt = 0; mt < 4; ++mt)
            afrag[mt] = *reinterpret_cast<const s16x8*>(a_lds + (mt * 16 + c) * KT + g * 8);
#pragma unroll
        for (int nt = 0; nt < 4; ++nt)
            bfrag[nt] = *reinterpret_cast<const s16x8*>(b_lds + (nbase + nt * 16 + c) * KT + g * 8);
#pragma unroll
        for (int mt = 0; mt < 4; ++mt)
#pragma unroll
            for (int nt = 0; nt < 4; ++nt)
                acc[mt][nt] = __builtin_amdgcn_mfma_f32_16x16x32_bf16(
                                  afrag[mt], bfrag[nt], acc[mt][nt], 0, 0, 0);
    }

    // --- fused epilogue: relu(att1 + att2) . Wfull, per-row reduce ---
    // C-frag mapping (verified): col = lane&15, row = (lane>>4)*4 + reg
#pragma unroll
    for (int mt = 0; mt < 4; ++mt) {
#pragma unroll
        for (int q = 0; q < 4; ++q) {
            const int row_local = mt * 16 + g * 4 + q;
            const int R = block_row + row_local;
            const int b = R / P_;
            float s = 0.f;
#pragma unroll
            for (int nt = 0; nt < 4; ++nt) {
                const int n = nbase + nt * 16 + c;
                float v = acc[mt][nt][q] + att2p[(size_t)b * DA_ + n];
                v = fmaxf(v, 0.f);
                s += v * Wfull[n];
            }
            // reduce across the 16 lanes sharing this row
#pragma unroll
            for (int off = 1; off < 16; off <<= 1)
                s += __shfl_xor(s, off, 64);
            if (c == 0) red[row_local][wave] = s;
        }
    }
    __syncthreads();
    if (tid < BM) {
        float t = 0.f;
#pragma unroll
        for (int w = 0; w < 8; ++w) t += red[tid][w];
        att[block_row + tid] = t + bfull[0];
    }
}

// ---------------------------------------------------------------------------
// Kernel 3: softmax over P per batch -> alpha (written straight to d_out)
// ---------------------------------------------------------------------------
__global__ __launch_bounds__(256) void softmax_kernel(
        const float* __restrict__ att, float* __restrict__ alpha) {
    const int b = blockIdx.x;
    const int t = threadIdx.x;
    __shared__ float sred[4];
    float v = (t < P_) ? att[(size_t)b * P_ + t] : -1e30f;
    float m = v;
#pragma unroll
    for (int off = 1; off < 64; off <<= 1) m = fmaxf(m, __shfl_xor(m, off, 64));
    if ((t & 63) == 0) sred[t >> 6] = m;
    __syncthreads();
    const float mall = fmaxf(fmaxf(sred[0], sred[1]), fmaxf(sred[2], sred[3]));
    __syncthreads();
    float e = (t < P_) ? expf(v - mall) : 0.f;
    float s = e;
#pragma unroll
    for (int off = 1; off < 64; off <<= 1) s += __shfl_xor(s, off, 64);
    if ((t & 63) == 0) sred[t >> 6] = s;
    __syncthreads();
    const float stot = sred[0] + sred[1] + sred[2] + sred[3];
    if (t < P_) alpha[(size_t)b * P_ + t] = e / stot;
}

// ---------------------------------------------------------------------------
// Kernel 4: context[b][e] = sum_p alpha[b][p] * enc[b][p][e]   (streaming pass)
// ---------------------------------------------------------------------------
__global__ __launch_bounds__(256) void context_kernel(
        const float* __restrict__ enc, const float* __restrict__ alpha,
        float* __restrict__ ctx) {
    const int b = blockIdx.x;
    const int e = blockIdx.y * 1024 + threadIdx.x * 4;
    __shared__ float s_alpha[P_];
    if (threadIdx.x < P_) s_alpha[threadIdx.x] = alpha[(size_t)b * P_ + threadIdx.x];
    __syncthreads();
    f32x4 acc = {0.f, 0.f, 0.f, 0.f};
    const float* base = enc + (size_t)b * P_ * DE_ + e;
#pragma unroll 4
    for (int p = 0; p < P_; ++p) {
        f32x4 v = *reinterpret_cast<const f32x4*>(base + (size_t)p * DE_);
        acc += s_alpha[p] * v;
    }
    *reinterpret_cast<f32x4*>(ctx + (size_t)b * DE_ + e) = acc;
}

// ---------------------------------------------------------------------------
extern "C" void kernel_launch(void* const* d_in, const int* in_sizes, int n_in,
                              void* d_out, int out_size, void* d_ws, size_t ws_size,
                              hipStream_t stream) {
    const float* enc    = (const float*)d_in[0];   // [B,P,DE]
    const float* dh     = (const float*)d_in[1];   // [B,DD]
    const float* W_enc  = (const float*)d_in[2];   // [DE,DA]
    const float* b_enc  = (const float*)d_in[3];   // [DA]
    const float* W_dec  = (const float*)d_in[4];   // [DD,DA]
    const float* b_dec  = (const float*)d_in[5];   // [DA]
    const float* W_full = (const float*)d_in[6];   // [DA,1]
    const float* b_full = (const float*)d_in[7];   // [1]

    float* out       = (float*)d_out;
    float* ctx_out   = out;                 // [B,DE] = 524288 floats
    float* alpha_out = out + (size_t)B_ * DE_;  // [B,P] = 50176 floats

    char* ws = (char*)d_ws;
    __hip_bfloat16* Bp = (__hip_bfloat16*)ws;                       // 2 MB
    float* att2p = (float*)(ws + 2u * 1024 * 1024);                 // 512 KB
    float* att   = (float*)(ws + 2u * 1024 * 1024 + 512u * 1024);   // ~200 KB

    pack_wenc   <<<dim3(64, 4),   256, 0, stream>>>(W_enc, Bp);
    att2_kernel <<<B_,            512, 0, stream>>>(dh, W_dec, b_dec, b_enc, att2p);
    gemm_att    <<<M_ / BM,       512, 0, stream>>>(enc, Bp, att2p, W_full, b_full, att);
    softmax_kernel<<<B_,          256, 0, stream>>>(att, alpha_out);
    context_kernel<<<dim3(B_, 2), 256, 0, stream>>>(enc, alpha_out, ctx_out);
}

// Round 2
// 312.128 us; speedup vs baseline: 1.0289x; 1.0289x over previous
//
#include <hip/hip_runtime.h>
#include <hip/hip_bf16.h>
#include <cstddef>

#define B_   256
#define P_   196
#define DE_  2048
#define DD_  512
#define DA_  512
#define M_   (B_*P_)   // 50176

#define BM   112       // 448 blocks exactly; 448/256 CU = 1.75 -> 87.5% balance
#define KT   32        // K per MFMA step

typedef __attribute__((ext_vector_type(4))) float f32x4;
typedef __attribute__((ext_vector_type(8))) short s16x8;

static __device__ __forceinline__ short f2bf(float x) {
    __hip_bfloat16 h = __float2bfloat16(x);
    return *reinterpret_cast<short*>(&h);
}

#define GLOAD_LDS16(g, l) __builtin_amdgcn_global_load_lds( \
    (const __attribute__((address_space(1))) void*)(g),     \
    (__attribute__((address_space(3))) void*)(l), 16, 0, 0)

// ---------------------------------------------------------------------------
// Kernel 0: pack W_enc [K=2048][N=512] fp32 -> bf16, fragment-ready + swizzled:
//   tile kt (k-chunk of 32): elem pos = n*32 + slot'*8 + j, where the element
//   is W[kt*32 + s*8 + j][n] and slot' = s ^ ((n>>1)&3)  (bank-conflict swizzle)
// global_load_lds then copies this linearly; the GEMM's ds_read applies the
// same swizzle -> both-sides-consistent (rule #21).
// ---------------------------------------------------------------------------
__global__ void pack_wenc(const float* __restrict__ W, __hip_bfloat16* __restrict__ out) {
    __shared__ float lds[KT][128 + 1];
    const int kt = blockIdx.x;           // 0..63
    const int n0 = blockIdx.y * 128;
    const int t  = threadIdx.x;          // 0..255
#pragma unroll
    for (int i = 0; i < 16; ++i) {
        int e  = t + i * 256;            // 0..4095
        int kl = e >> 7;                 // 0..31
        int nl = e & 127;
        lds[kl][nl] = W[(size_t)(kt * KT + kl) * DA_ + n0 + nl];
    }
    __syncthreads();
    short* o16 = reinterpret_cast<short*>(out);
#pragma unroll
    for (int i = 0; i < 2; ++i) {
        int task = t + i * 256;          // 0..511
        int nl   = task >> 2;            // 0..127
        int s    = task & 3;             // logical 8-slot
        int n    = n0 + nl;
        int sp   = s ^ ((n >> 1) & 3);   // swizzled slot
        s16x8 w;
#pragma unroll
        for (int j = 0; j < 8; ++j)
            w[j] = f2bf(lds[s * 8 + j][nl]);
        *reinterpret_cast<s16x8*>(o16 + (size_t)kt * (DA_ * KT) + n * KT + sp * 8) = w;
    }
}

// ---------------------------------------------------------------------------
// Kernel 1: att2p[b][a] = dh[b,:] @ W_dec[:,a] + b_dec[a] + b_enc[a]
// ---------------------------------------------------------------------------
__global__ __launch_bounds__(512) void att2_kernel(
        const float* __restrict__ dh, const float* __restrict__ W_dec,
        const float* __restrict__ b_dec, const float* __restrict__ b_enc,
        float* __restrict__ att2p) {
    __shared__ float s_dh[DD_];
    const int b = blockIdx.x;
    const int a = threadIdx.x;
    s_dh[a] = dh[(size_t)b * DD_ + a];
    __syncthreads();
    float acc = 0.f;
#pragma unroll 8
    for (int k = 0; k < DD_; ++k)
        acc += s_dh[k] * W_dec[(size_t)k * DA_ + a];
    att2p[(size_t)b * DA_ + a] = acc + b_dec[a] + b_enc[a];
}

// ---------------------------------------------------------------------------
// Kernel 2: GEMM M=50176 K=2048 N=512, bf16 MFMA, fused relu/dot epilogue.
// Block: 512 thr (8 waves, 1x8), tile 112 x 512. Wave w: cols [w*64, w*64+64).
// A swizzle-staged manually (fp32->bf16), B via global_load_lds (pre-swizzled).
// ---------------------------------------------------------------------------
__global__ __launch_bounds__(512, 2) void gemm_att(
        const float* __restrict__ enc, const __hip_bfloat16* __restrict__ Bp,
        const float* __restrict__ att2p, const float* __restrict__ Wfull,
        const float* __restrict__ bfull, float* __restrict__ att) {
    __shared__ __hip_bfloat16 a_lds[BM * KT];    // 7 KB  (swizzled slots)
    __shared__ __hip_bfloat16 b_lds[DA_ * KT];   // 32 KB (swizzled slots)
    __shared__ float red[BM][8];                 // 3.5 KB

    const int tid  = threadIdx.x;
    const int wave = tid >> 6;
    const int lane = tid & 63;
    const int g    = lane >> 4;        // k-group 0..3
    const int c    = lane & 15;        // row (A) / col (B) within frag
    const int block_row = blockIdx.x * BM;
    const int nbase = wave * 64;

    // swizzled 8-elem slot shared by A and B frag reads: g ^ ((row>>1)&3), row≡c (mod 16 strides)
    const int slot8 = (g ^ ((c >> 1) & 3)) * 8;

    // A-staging role: thread handles row ar (0..111), k-slot aq (0..3)
    const int ar = tid >> 2;
    const int aq = tid & 3;
    const bool a_active = (tid < BM * 4);
    __hip_bfloat16* a_dst = a_lds + ar * KT + (aq ^ ((ar >> 1) & 3)) * 8;
    const float* a_src = enc + (size_t)(block_row + ar) * DE_ + aq * 8;

    f32x4 acc[7][4] = {};

    for (int kt = 0; kt < DE_ / KT; ++kt) {
        __syncthreads();   // previous iteration's readers done
        // --- B: async global->LDS, 4 x 8KB issues (pre-swizzled layout) ---
        {
            const char* bsrc = (const char*)Bp + (size_t)kt * (DA_ * KT * 2) + (size_t)tid * 16;
            char*       bdst = (char*)b_lds + wave * 1024;
#pragma unroll
            for (int i = 0; i < 4; ++i)
                GLOAD_LDS16(bsrc + i * 8192, bdst + i * 8192);
        }
        // --- A: 112 rows x 32 k, fp32 -> bf16, swizzled ds_write_b128 ---
        if (a_active) {
            f32x4 v0 = *reinterpret_cast<const f32x4*>(a_src + kt * KT);
            f32x4 v1 = *reinterpret_cast<const f32x4*>(a_src + kt * KT + 4);
            s16x8 w;
            w[0] = f2bf(v0.x); w[1] = f2bf(v0.y); w[2] = f2bf(v0.z); w[3] = f2bf(v0.w);
            w[4] = f2bf(v1.x); w[5] = f2bf(v1.y); w[6] = f2bf(v1.z); w[7] = f2bf(v1.w);
            *reinterpret_cast<s16x8*>(a_dst) = w;
        }
        __syncthreads();   // drains vmcnt (global_load_lds) + lgkmcnt (ds_write)
        // --- fragments + MFMA ---
        s16x8 afrag[7], bfrag[4];
#pragma unroll
        for (int mt = 0; mt < 7; ++mt)
            afrag[mt] = *reinterpret_cast<const s16x8*>(a_lds + (mt * 16 + c) * KT + slot8);
#pragma unroll
        for (int nt = 0; nt < 4; ++nt)
            bfrag[nt] = *reinterpret_cast<const s16x8*>(b_lds + (nbase + nt * 16 + c) * KT + slot8);
#pragma unroll
        for (int mt = 0; mt < 7; ++mt)
#pragma unroll
            for (int nt = 0; nt < 4; ++nt)
                acc[mt][nt] = __builtin_amdgcn_mfma_f32_16x16x32_bf16(
                                  afrag[mt], bfrag[nt], acc[mt][nt], 0, 0, 0);
    }

    // --- fused epilogue: att[R] = sum_n relu(att1+att2) * Wfull  (+bfull later) ---
    const int b0    = block_row / P_;
    const int b1    = min(b0 + 1, B_ - 1);
    const int split = (b0 + 1) * P_;     // rows >= split belong to b1
    float wf[4], a20[4], a21[4];
#pragma unroll
    for (int nt = 0; nt < 4; ++nt) {
        const int n = nbase + nt * 16 + c;
        wf[nt]  = Wfull[n];
        a20[nt] = att2p[(size_t)b0 * DA_ + n];
        a21[nt] = att2p[(size_t)b1 * DA_ + n];
    }
#pragma unroll
    for (int mt = 0; mt < 7; ++mt) {
#pragma unroll
        for (int q = 0; q < 4; ++q) {
            const int row_local = mt * 16 + g * 4 + q;
            const int R = block_row + row_local;
            const bool hi = (R >= split);
            float s = 0.f;
#pragma unroll
            for (int nt = 0; nt < 4; ++nt) {
                float a2 = hi ? a21[nt] : a20[nt];
                float v  = acc[mt][nt][q] + a2;
                v = fmaxf(v, 0.f);
                s += v * wf[nt];
            }
#pragma unroll
            for (int off = 1; off < 16; off <<= 1)
                s += __shfl_xor(s, off, 64);
            if (c == 0) red[row_local][wave] = s;
        }
    }
    __syncthreads();
    if (tid < BM) {
        float t = 0.f;
#pragma unroll
        for (int w = 0; w < 8; ++w) t += red[tid][w];
        att[block_row + tid] = t + bfull[0];
    }
}

// ---------------------------------------------------------------------------
// Kernel 3: softmax over P per batch -> alpha
// ---------------------------------------------------------------------------
__global__ __launch_bounds__(256) void softmax_kernel(
        const float* __restrict__ att, float* __restrict__ alpha) {
    const int b = blockIdx.x;
    const int t = threadIdx.x;
    __shared__ float sred[4];
    float v = (t < P_) ? att[(size_t)b * P_ + t] : -1e30f;
    float m = v;
#pragma unroll
    for (int off = 1; off < 64; off <<= 1) m = fmaxf(m, __shfl_xor(m, off, 64));
    if ((t & 63) == 0) sred[t >> 6] = m;
    __syncthreads();
    const float mall = fmaxf(fmaxf(sred[0], sred[1]), fmaxf(sred[2], sred[3]));
    __syncthreads();
    float e = (t < P_) ? expf(v - mall) : 0.f;
    float s = e;
#pragma unroll
    for (int off = 1; off < 64; off <<= 1) s += __shfl_xor(s, off, 64);
    if ((t & 63) == 0) sred[t >> 6] = s;
    __syncthreads();
    const float stot = sred[0] + sred[1] + sred[2] + sred[3];
    if (t < P_) alpha[(size_t)b * P_ + t] = e / stot;
}

// ---------------------------------------------------------------------------
// Kernel 4: context[b][e] = sum_p alpha[b][p] * enc[b][p][e]
// ---------------------------------------------------------------------------
__global__ __launch_bounds__(256) void context_kernel(
        const float* __restrict__ enc, const float* __restrict__ alpha,
        float* __restrict__ ctx) {
    const int b = blockIdx.x;
    const int e = blockIdx.y * 1024 + threadIdx.x * 4;
    __shared__ float s_alpha[P_];
    if (threadIdx.x < P_) s_alpha[threadIdx.x] = alpha[(size_t)b * P_ + threadIdx.x];
    __syncthreads();
    f32x4 acc = {0.f, 0.f, 0.f, 0.f};
    const float* base = enc + (size_t)b * P_ * DE_ + e;
#pragma unroll 4
    for (int p = 0; p < P_; ++p) {
        f32x4 v = *reinterpret_cast<const f32x4*>(base + (size_t)p * DE_);
        acc += s_alpha[p] * v;
    }
    *reinterpret_cast<f32x4*>(ctx + (size_t)b * DE_ + e) = acc;
}

// ---------------------------------------------------------------------------
extern "C" void kernel_launch(void* const* d_in, const int* in_sizes, int n_in,
                              void* d_out, int out_size, void* d_ws, size_t ws_size,
                              hipStream_t stream) {
    const float* enc    = (const float*)d_in[0];
    const float* dh     = (const float*)d_in[1];
    const float* W_enc  = (const float*)d_in[2];
    const float* b_enc  = (const float*)d_in[3];
    const float* W_dec  = (const float*)d_in[4];
    const float* b_dec  = (const float*)d_in[5];
    const float* W_full = (const float*)d_in[6];
    const float* b_full = (const float*)d_in[7];

    float* out       = (float*)d_out;
    float* ctx_out   = out;                       // [B,DE]
    float* alpha_out = out + (size_t)B_ * DE_;    // [B,P]

    char* ws = (char*)d_ws;
    __hip_bfloat16* Bp = (__hip_bfloat16*)ws;                        // 2 MB
    float* att2p = (float*)(ws + 2u * 1024 * 1024);                  // 512 KB
    float* att   = (float*)(ws + 2u * 1024 * 1024 + 512u * 1024);    // 200 KB

    pack_wenc   <<<dim3(64, 4),     256, 0, stream>>>(W_enc, Bp);
    att2_kernel <<<B_,              512, 0, stream>>>(dh, W_dec, b_dec, b_enc, att2p);
    gemm_att    <<<M_ / BM,         512, 0, stream>>>(enc, Bp, att2p, W_full, b_full, att);
    softmax_kernel<<<B_,            256, 0, stream>>>(att, alpha_out);
    context_kernel<<<dim3(B_, 2),   256, 0, stream>>>(enc, alpha_out, ctx_out);
}

// Round 3
// 274.925 us; speedup vs baseline: 1.1682x; 1.1353x over previous
//
#include <hip/hip_runtime.h>
#include <hip/hip_bf16.h>
#include <cstddef>

#define B_   256
#define P_   196
#define DE_  2048
#define DD_  512
#define DA_  512
#define M_   (B_*P_)   // 50176

#define BM   112       // grid 448
#define KT   32        // K per stage
#define NKT  (DE_/KT)  // 64
#define AROWS 128      // a_lds rows incl. 16-row junk stripe (uniform staging)

typedef __attribute__((ext_vector_type(4))) float f32x4;
typedef __attribute__((ext_vector_type(8))) short s16x8;

static __device__ __forceinline__ short f2bf(float x) {
    __hip_bfloat16 h = __float2bfloat16(x);
    return *reinterpret_cast<short*>(&h);
}

#define GLOAD_LDS16(g, l) __builtin_amdgcn_global_load_lds( \
    (const __attribute__((address_space(1))) void*)(g),     \
    (__attribute__((address_space(3))) void*)(l), 16, 0, 0)

// ---------------------------------------------------------------------------
// Kernel 0: pack W_enc [K][N] fp32 -> bf16 fragment-ready + XOR-swizzled
// ---------------------------------------------------------------------------
__global__ void pack_wenc(const float* __restrict__ W, __hip_bfloat16* __restrict__ out) {
    __shared__ float lds[KT][128 + 1];
    const int kt = blockIdx.x;
    const int n0 = blockIdx.y * 128;
    const int t  = threadIdx.x;
#pragma unroll
    for (int i = 0; i < 16; ++i) {
        int e  = t + i * 256;
        int kl = e >> 7;
        int nl = e & 127;
        lds[kl][nl] = W[(size_t)(kt * KT + kl) * DA_ + n0 + nl];
    }
    __syncthreads();
    short* o16 = reinterpret_cast<short*>(out);
#pragma unroll
    for (int i = 0; i < 2; ++i) {
        int task = t + i * 256;
        int nl   = task >> 2;
        int s    = task & 3;
        int n    = n0 + nl;
        int sp   = s ^ ((n >> 1) & 3);
        s16x8 w;
#pragma unroll
        for (int j = 0; j < 8; ++j)
            w[j] = f2bf(lds[s * 8 + j][nl]);
        *reinterpret_cast<s16x8*>(o16 + (size_t)kt * (DA_ * KT) + n * KT + sp * 8) = w;
    }
}

// ---------------------------------------------------------------------------
// Kernel 1: att2p[b][a] = dh[b,:] @ W_dec[:,a] + b_dec[a] + b_enc[a]
// ---------------------------------------------------------------------------
__global__ __launch_bounds__(512) void att2_kernel(
        const float* __restrict__ dh, const float* __restrict__ W_dec,
        const float* __restrict__ b_dec, const float* __restrict__ b_enc,
        float* __restrict__ att2p) {
    __shared__ float s_dh[DD_];
    const int b = blockIdx.x;
    const int a = threadIdx.x;
    s_dh[a] = dh[(size_t)b * DD_ + a];
    __syncthreads();
    float acc = 0.f;
#pragma unroll 8
    for (int k = 0; k < DD_; ++k)
        acc += s_dh[k] * W_dec[(size_t)k * DA_ + a];
    att2p[(size_t)b * DA_ + a] = acc + b_dec[a] + b_enc[a];
}

// ---------------------------------------------------------------------------
// Kernel 2: GEMM 50176x512x2048 bf16 MFMA, 2-phase double-buffered pipeline:
//   raw s_barrier + counted vmcnt (no __syncthreads vmcnt(0) drain),
//   B(t+1) via global_load_lds issued at top of iter t,
//   A prefetched 2 tiles ahead into regs, consumed (cvt+ds_write) after MFMA.
// ---------------------------------------------------------------------------
__global__ __launch_bounds__(512, 1) void gemm_att(
        const float* __restrict__ enc, const __hip_bfloat16* __restrict__ Bp,
        const float* __restrict__ att2p, const float* __restrict__ Wfull,
        const float* __restrict__ bfull, float* __restrict__ att) {
    __shared__ __hip_bfloat16 a_lds0[AROWS * KT];   // 8 KB each
    __shared__ __hip_bfloat16 a_lds1[AROWS * KT];
    __shared__ __hip_bfloat16 b_lds0[DA_ * KT];     // 32 KB each
    __shared__ __hip_bfloat16 b_lds1[DA_ * KT];
    __shared__ float red[BM][8];

    const int tid  = threadIdx.x;
    const int wave = tid >> 6;
    const int lane = tid & 63;
    const int g    = lane >> 4;
    const int c    = lane & 15;
    const int block_row = blockIdx.x * BM;
    const int nbase = wave * 64;
    const int slot8 = (g ^ ((c >> 1) & 3)) * 8;

    // A staging role: ALL 512 threads (rows 112..127 -> junk stripe, dup src rows 0..15)
    const int ar   = tid >> 2;                 // 0..127
    const int aq   = tid & 3;                  // 0..3
    const int lrow = (ar < BM) ? ar : (ar & 15);
    const int a_woff = ar * KT + (aq ^ ((ar >> 1) & 3)) * 8;   // elements
    const float* ap = enc + (size_t)(block_row + lrow) * DE_ + aq * 8;

    f32x4 acc[7][4] = {};
    f32x4 pa0, pa1, pb0, pb1;   // A prefetch sets (even/odd tiles)

#define STORE_A(dstbase, v0, v1) do {                                   \
        s16x8 w_;                                                       \
        w_[0]=f2bf((v0).x); w_[1]=f2bf((v0).y); w_[2]=f2bf((v0).z); w_[3]=f2bf((v0).w); \
        w_[4]=f2bf((v1).x); w_[5]=f2bf((v1).y); w_[6]=f2bf((v1).z); w_[7]=f2bf((v1).w); \
        *reinterpret_cast<s16x8*>((dstbase) + a_woff) = w_;             \
    } while (0)

#define ISSUE_B(T, dstb) do {                                           \
        const char* bs_ = (const char*)Bp + (size_t)(T) * (DA_*KT*2) + (size_t)tid * 16; \
        char* bd_ = (char*)(dstb) + (size_t)tid * 16;                   \
        GLOAD_LDS16(bs_,           bd_);                                \
        GLOAD_LDS16(bs_ +  8192,   bd_ +  8192);                        \
        GLOAD_LDS16(bs_ + 16384,   bd_ + 16384);                        \
        GLOAD_LDS16(bs_ + 24576,   bd_ + 24576);                        \
    } while (0)

#define FRAGS_MFMA(abuf, bbuf) do {                                     \
        s16x8 af[7], bf[4];                                             \
        _Pragma("unroll")                                               \
        for (int mt = 0; mt < 7; ++mt)                                  \
            af[mt] = *reinterpret_cast<const s16x8*>((abuf) + (mt*16 + c) * KT + slot8); \
        _Pragma("unroll")                                               \
        for (int nt = 0; nt < 4; ++nt)                                  \
            bf[nt] = *reinterpret_cast<const s16x8*>((bbuf) + (nbase + nt*16 + c) * KT + slot8); \
        _Pragma("unroll")                                               \
        for (int mt = 0; mt < 7; ++mt)                                  \
            _Pragma("unroll")                                           \
            for (int nt = 0; nt < 4; ++nt)                              \
                acc[mt][nt] = __builtin_amdgcn_mfma_f32_16x16x32_bf16(  \
                                  af[mt], bf[nt], acc[mt][nt], 0, 0, 0);\
    } while (0)

#define FENCE_AFTER_BARRIER() do {                                      \
        asm volatile("" ::: "memory");                                  \
        __builtin_amdgcn_sched_barrier(0);                              \
    } while (0)

    // ---- prologue: tile 0 fully staged, A(1) in flight ----
    pa0 = *reinterpret_cast<const f32x4*>(ap);            // A(0)
    pa1 = *reinterpret_cast<const f32x4*>(ap + 4);
    ISSUE_B(0, b_lds0);
    pb0 = *reinterpret_cast<const f32x4*>(ap + KT);       // A(1)
    pb1 = *reinterpret_cast<const f32x4*>(ap + KT + 4);
    STORE_A(a_lds0, pa0, pa1);                            // compiler waits A(0) only
    asm volatile("s_waitcnt vmcnt(2) lgkmcnt(0)" ::: "memory");  // B(0) done, A(1) in flight
    __builtin_amdgcn_s_barrier();
    FENCE_AFTER_BARRIER();

    // ---- main loop: t = 0..61, unrolled by 2 ----
#define ITER(T, ACUR, BCUR, ANXT, BNXT, C0, C1, I0, I1) do {            \
        ISSUE_B((T)+1, BNXT);                                           \
        I0 = *reinterpret_cast<const f32x4*>(ap + ((T)+2 - (T)/2*2) * 0 + 0); \
        (void)0;                                                        \
    } while (0)
#undef ITER

    const float* ap_it = ap;   // advanced by 2*KT floats per unrolled pair
#pragma clang loop unroll(disable)
    for (int kt = 0; kt < 62; kt += 2) {
        // ---- iter even: cur = buf0, consume A(kt+1)=setB, issue A(kt+2)->setA ----
        ISSUE_B(kt + 1, b_lds1);
        pa0 = *reinterpret_cast<const f32x4*>(ap_it + 2 * KT);
        pa1 = *reinterpret_cast<const f32x4*>(ap_it + 2 * KT + 4);
        FRAGS_MFMA(a_lds0, b_lds0);
        STORE_A(a_lds1, pb0, pb1);
        asm volatile("s_waitcnt vmcnt(2) lgkmcnt(0)" ::: "memory");
        __builtin_amdgcn_s_barrier();
        FENCE_AFTER_BARRIER();
        // ---- iter odd: cur = buf1, consume A(kt+2)=setA, issue A(kt+3)->setB ----
        ISSUE_B(kt + 2, b_lds0);
        pb0 = *reinterpret_cast<const f32x4*>(ap_it + 3 * KT);
        pb1 = *reinterpret_cast<const f32x4*>(ap_it + 3 * KT + 4);
        FRAGS_MFMA(a_lds1, b_lds1);
        STORE_A(a_lds0, pa0, pa1);
        asm volatile("s_waitcnt vmcnt(2) lgkmcnt(0)" ::: "memory");
        __builtin_amdgcn_s_barrier();
        FENCE_AFTER_BARRIER();
        ap_it += 2 * KT;
    }
    // ---- t = 62: consume A(63)=setB, no A issue ----
    ISSUE_B(63, b_lds1);
    FRAGS_MFMA(a_lds0, b_lds0);
    STORE_A(a_lds1, pb0, pb1);
    asm volatile("s_waitcnt vmcnt(0) lgkmcnt(0)" ::: "memory");
    __builtin_amdgcn_s_barrier();
    FENCE_AFTER_BARRIER();
    // ---- t = 63: pure compute ----
    FRAGS_MFMA(a_lds1, b_lds1);

    // ---- fused epilogue ----
    const int b0    = block_row / P_;
    const int b1    = min(b0 + 1, B_ - 1);
    const int split = (b0 + 1) * P_;
    float wf[4], a20[4], a21[4];
#pragma unroll
    for (int nt = 0; nt < 4; ++nt) {
        const int n = nbase + nt * 16 + c;
        wf[nt]  = Wfull[n];
        a20[nt] = att2p[(size_t)b0 * DA_ + n];
        a21[nt] = att2p[(size_t)b1 * DA_ + n];
    }
#pragma unroll
    for (int mt = 0; mt < 7; ++mt) {
#pragma unroll
        for (int q = 0; q < 4; ++q) {
            const int row_local = mt * 16 + g * 4 + q;
            const int R = block_row + row_local;
            const bool hi = (R >= split);
            float s = 0.f;
#pragma unroll
            for (int nt = 0; nt < 4; ++nt) {
                float a2 = hi ? a21[nt] : a20[nt];
                float v  = acc[mt][nt][q] + a2;
                v = fmaxf(v, 0.f);
                s += v * wf[nt];
            }
#pragma unroll
            for (int off = 1; off < 16; off <<= 1)
                s += __shfl_xor(s, off, 64);
            if (c == 0) red[row_local][wave] = s;
        }
    }
    __syncthreads();
    if (tid < BM) {
        float t = 0.f;
#pragma unroll
        for (int w = 0; w < 8; ++w) t += red[tid][w];
        att[block_row + tid] = t + bfull[0];
    }
#undef STORE_A
#undef ISSUE_B
#undef FRAGS_MFMA
#undef FENCE_AFTER_BARRIER
}

// ---------------------------------------------------------------------------
// Kernel 3: softmax over P per batch -> alpha
// ---------------------------------------------------------------------------
__global__ __launch_bounds__(256) void softmax_kernel(
        const float* __restrict__ att, float* __restrict__ alpha) {
    const int b = blockIdx.x;
    const int t = threadIdx.x;
    __shared__ float sred[4];
    float v = (t < P_) ? att[(size_t)b * P_ + t] : -1e30f;
    float m = v;
#pragma unroll
    for (int off = 1; off < 64; off <<= 1) m = fmaxf(m, __shfl_xor(m, off, 64));
    if ((t & 63) == 0) sred[t >> 6] = m;
    __syncthreads();
    const float mall = fmaxf(fmaxf(sred[0], sred[1]), fmaxf(sred[2], sred[3]));
    __syncthreads();
    float e = (t < P_) ? expf(v - mall) : 0.f;
    float s = e;
#pragma unroll
    for (int off = 1; off < 64; off <<= 1) s += __shfl_xor(s, off, 64);
    if ((t & 63) == 0) sred[t >> 6] = s;
    __syncthreads();
    const float stot = sred[0] + sred[1] + sred[2] + sred[3];
    if (t < P_) alpha[(size_t)b * P_ + t] = e / stot;
}

// ---------------------------------------------------------------------------
// Kernel 4: context[b][e] = sum_p alpha[b][p] * enc[b][p][e]
// ---------------------------------------------------------------------------
__global__ __launch_bounds__(256) void context_kernel(
        const float* __restrict__ enc, const float* __restrict__ alpha,
        float* __restrict__ ctx) {
    const int b = blockIdx.x;
    const int e = blockIdx.y * 1024 + threadIdx.x * 4;
    __shared__ float s_alpha[P_];
    if (threadIdx.x < P_) s_alpha[threadIdx.x] = alpha[(size_t)b * P_ + threadIdx.x];
    __syncthreads();
    f32x4 acc = {0.f, 0.f, 0.f, 0.f};
    const float* base = enc + (size_t)b * P_ * DE_ + e;
#pragma unroll 4
    for (int p = 0; p < P_; ++p) {
        f32x4 v = *reinterpret_cast<const f32x4*>(base + (size_t)p * DE_);
        acc += s_alpha[p] * v;
    }
    *reinterpret_cast<f32x4*>(ctx + (size_t)b * DE_ + e) = acc;
}

// ---------------------------------------------------------------------------
extern "C" void kernel_launch(void* const* d_in, const int* in_sizes, int n_in,
                              void* d_out, int out_size, void* d_ws, size_t ws_size,
                              hipStream_t stream) {
    const float* enc    = (const float*)d_in[0];
    const float* dh     = (const float*)d_in[1];
    const float* W_enc  = (const float*)d_in[2];
    const float* b_enc  = (const float*)d_in[3];
    const float* W_dec  = (const float*)d_in[4];
    const float* b_dec  = (const float*)d_in[5];
    const float* W_full = (const float*)d_in[6];
    const float* b_full = (const float*)d_in[7];

    float* out       = (float*)d_out;
    float* ctx_out   = out;                       // [B,DE]
    float* alpha_out = out + (size_t)B_ * DE_;    // [B,P]

    char* ws = (char*)d_ws;
    __hip_bfloat16* Bp = (__hip_bfloat16*)ws;                        // 2 MB
    float* att2p = (float*)(ws + 2u * 1024 * 1024);                  // 512 KB
    float* att   = (float*)(ws + 2u * 1024 * 1024 + 512u * 1024);    // 200 KB

    pack_wenc   <<<dim3(64, 4),     256, 0, stream>>>(W_enc, Bp);
    att2_kernel <<<B_,              512, 0, stream>>>(dh, W_dec, b_dec, b_enc, att2p);
    gemm_att    <<<M_ / BM,         512, 0, stream>>>(enc, Bp, att2p, W_full, b_full, att);
    softmax_kernel<<<B_,            256, 0, stream>>>(att, alpha_out);
    context_kernel<<<dim3(B_, 2),   256, 0, stream>>>(enc, alpha_out, ctx_out);
}